// Round 14
// baseline (1327.199 us; speedup 1.0000x reference)
//
#include <hip/hip_runtime.h>
#include <hip/hip_bf16.h>

#define Bv 8
#define Tv 16
#define Hv 64
#define Wv 64
#define Cv 16
#define HID 64
#define PH 66   // spatially padded (1-px halo)

typedef short short8 __attribute__((ext_vector_type(8)));
typedef float f32x4 __attribute__((ext_vector_type(4)));
typedef unsigned short u16x8 __attribute__((ext_vector_type(8)));

__device__ __forceinline__ unsigned short f2bf(float x) {
  union { float f; unsigned int u; } v; v.f = x;
  unsigned int r = v.u + 0x7FFF + ((v.u >> 16) & 1);   // RNE
  return (unsigned short)(r >> 16);
}
__device__ __forceinline__ float sigmoid_f(float x) {
  return 1.f / (1.f + __expf(-x));
}
__device__ __forceinline__ float tanh_f(float x) {
  float e = __expf(2.f * x);
  return 1.f - 2.f / (e + 1.f);
}

// ---- W1 re-layout, SOURCE-MAJOR: chunks 0..17 = h0 rows (tap*128 + (cc&1)*32),
// chunks 18..35 = h1 rows (tap*128 + 64 + ((cc-18)&1)*32). T0 = prefix 0..17.
// Chunk (16KB): [wn(4)][g(4)][lane(64)][e(8)]; lane l=(kg*16+r) holds
// B[k=kg*8+e][col' = wn*64+g*16+r], orig col = g*64 + wn*16 + r.
__global__ void relayout_w1(const float* __restrict__ W1, unsigned short* __restrict__ out) {
  int o = blockIdx.x * 256 + threadIdx.x;            // 36*8192 = 294912
  if (o >= 36 * 8192) return;
  int cc = o >> 13, t = o & 8191;
  int wn = t >> 11, t2 = t & 2047;
  int g = t2 >> 9, t3 = t2 & 511;
  int l = t3 >> 3, e = t3 & 7;
  int kg = l >> 4, r = l & 15;
  int k = kg * 8 + e;
  int col = g * 64 + wn * 16 + r;
  int row;
  if (cc < 18) { int tap = cc >> 1; row = tap * 128 + (cc & 1) * 32 + k; }
  else { int h = cc - 18; int tap = h >> 1; row = tap * 128 + 64 + (h & 1) * 32 + k; }
  out[o] = f2bf(W1[(size_t)row * 256 + col]);
}

// ---- W0 re-layout with x-tap pairing (already source-major): 23 chunks.
// cc<4:  K = [tap 2cc ch0-15 | tap 2cc+1 ch0-15]; cc==4: [tap 8 | zeros];
// cc>=5: h chunks: tap=(cc-5)>>1, cgi=(cc-5)&1, rows 16+cgi*32+k. T0 = prefix 0..4.
__global__ void relayout_w0(const float* __restrict__ W0, unsigned short* __restrict__ out) {
  int o = blockIdx.x * 256 + threadIdx.x;            // 23*8192 = 188416
  if (o >= 23 * 8192) return;
  int cc = o >> 13, t = o & 8191;
  int wn = t >> 11, t2 = t & 2047;
  int g = t2 >> 9, t3 = t2 & 511;
  int l = t3 >> 3, e = t3 & 7;
  int kg = l >> 4, r = l & 15;
  int k = kg * 8 + e;
  int col = g * 64 + wn * 16 + r;
  float v = 0.f;
  if (cc < 4) {
    int tap = 2 * cc + (k >> 4);
    v = W0[(size_t)(tap * 80 + (k & 15)) * 256 + col];
  } else if (cc == 4) {
    if (k < 16) v = W0[(size_t)(8 * 80 + k) * 256 + col];
  } else {
    int hcc = cc - 5, tap = hcc >> 1, cgi = hcc & 1;
    v = W0[(size_t)(tap * 80 + 16 + cgi * 32 + k) * 256 + col];
  }
  out[o] = f2bf(v);
}

// ---- zero per call: both x buffers (16ch rows) + h halo rings
__global__ void zero_init(unsigned short* __restrict__ h0a, unsigned short* __restrict__ h0b,
                          unsigned short* __restrict__ h1a, unsigned short* __restrict__ h1b,
                          unsigned short* __restrict__ xb) {
  int idx = blockIdx.x * 256 + threadIdx.x;          // 16B chunks
  u16x8 z = {};
  const int XB_CH = (Bv * PH * PH * 16 * 2 * 2) / 16;  // two x buffers = 139392
  if (idx < XB_CH) { *(u16x8*)(xb + idx * 8) = z; return; }
  idx -= XB_CH;
  int bufi = idx / 16640;                            // 8 b x 260 px x 8 chunks
  if (bufi >= 4) return;
  int rem = idx - bufi * 16640;
  int b = rem / 2080, r2 = rem - b * 2080;
  int hp = r2 >> 3, c8 = r2 & 7;
  int y, x;
  if (hp < 66)       { y = 0;  x = hp; }
  else if (hp < 132) { y = 65; x = hp - 66; }
  else { int i2 = hp - 132; y = 1 + (i2 >> 1); x = (i2 & 1) * 65; }
  unsigned short* base = (bufi == 0) ? h0a : (bufi == 1) ? h0b : (bufi == 2) ? h1a : h1b;
  *(u16x8*)(base + ((size_t)((b * PH + y) * PH) + x) * 64 + c8 * 8) = z;
}

// ---- t=0 x conversion: enc fp32 -> padded bf16 [b][66][66][16]
__global__ void convert_x0(const float* __restrict__ enc, unsigned short* __restrict__ xb) {
  int idx = blockIdx.x * 256 + threadIdx.x;          // 32768
  int b = idx >> 12, pix = idx & 4095;
  int y = pix >> 6, x = pix & 63;
  const float* s = enc + ((size_t)(b * Tv + 0) * 4096 + pix) * 16;
  float4 f0 = *(const float4*)(s);
  float4 f1 = *(const float4*)(s + 4);
  float4 f2 = *(const float4*)(s + 8);
  float4 f3 = *(const float4*)(s + 12);
  u16x8 o0, o1;
  o0[0]=f2bf(f0.x); o0[1]=f2bf(f0.y); o0[2]=f2bf(f0.z); o0[3]=f2bf(f0.w);
  o0[4]=f2bf(f1.x); o0[5]=f2bf(f1.y); o0[6]=f2bf(f1.z); o0[7]=f2bf(f1.w);
  o1[0]=f2bf(f2.x); o1[1]=f2bf(f2.y); o1[2]=f2bf(f2.z); o1[3]=f2bf(f2.w);
  o1[4]=f2bf(f3.x); o1[5]=f2bf(f3.y); o1[6]=f2bf(f3.z); o1[7]=f2bf(f3.w);
  unsigned short* d = xb + ((size_t)((b * PH + y + 1) * PH) + (x + 1)) * 16;
  *(u16x8*)(d)     = o0;
  *(u16x8*)(d + 8) = o1;
}

// ---- one cell on a 128-px (16x8) x 256-gate-col tile: 8 waves (2wm x 4wn).
// W: block-cooperative LDS staging (16KB/chunk), 4 bufs, depth-3 in flight.
// A: DIRECT global->VGPR through L1 (4x wn-duplication absorbed by L1; LDS
// traffic/chunk drops 88KB -> 48KB). af prefetched depth-1 into the same regs
// after MFMA consumption (no ring -> no reg growth). Exact vmcnt: ops/iter =
// 2 gll + 4 af; steady vmcnt(16), edges 8/12/14. sched_barrier fences pin the
// segment order the counts assume. cell0 NC 5|23; cell1 NC 18|36 (T0=prefix).
template<int CELL, int NC>
__device__ __forceinline__ void cell_run(
    const char* __restrict__ A0, const char* __restrict__ A1,
    const char* __restrict__ Wr, const float* __restrict__ bias,
    float* __restrict__ cbuf, unsigned short* __restrict__ hout,
    float* __restrict__ h1fin, float* __restrict__ c1fin,
    char* lds, int b, int by, int bx, int tid)
{
  constexpr bool T0C = (CELL == 0) ? (NC == 5) : (NC == 18);
  const int l = tid & 63, w = tid >> 6;              // 8 waves
  const int wm = w >> 2, wn = w & 3;
  const int r = l & 15, kg = l >> 4;
  const int j = wn * 16 + r;

  // own-frag base pixel; mi stride = 2 rows = 2*PH (p = wm*64 + mi*16 + r)
  int pix0;
  {
    int p = wm * 64 + r;
    int y = by * 16 + (p >> 3), x = bx * 8 + (p & 7);
    pix0 = (b * PH + y) * PH + x;
  }
  const int zpix = b * PH * PH;                      // zeroed halo corner (x buf)

  auto ISSUE = [&](int cc, int buf) {                // W chunk cc -> LDS buf
    char* dst = lds + buf * 16384;
    const char* wp = Wr + (size_t)cc * 16384 + (unsigned)(w * 2048 + l * 16);
    __builtin_amdgcn_global_load_lds((const unsigned int*)wp,
                                     (unsigned int*)(dst + w * 2048), 16, 0, 0);
    __builtin_amdgcn_global_load_lds((const unsigned int*)(wp + 1024),
                                     (unsigned int*)(dst + w * 2048 + 1024), 16, 0, 0);
  };

  short8 af[4], bfv[4];

  auto LOADA = [&](int cc) {                         // af(cc) direct from global/L1
    if constexpr (CELL == 0) {
      if (cc < 5) {
        int tapA = 2 * cc, kyA = tapA / 3, kxA = tapA - kyA * 3;
#pragma unroll
        for (int mi = 0; mi < 4; ++mi) {
          int pm = pix0 + mi * (2 * PH);
          unsigned offA = (unsigned)((pm + kyA * PH + kxA) * 32 + kg * 16);
          unsigned offB;
          if (cc < 4) {
            int tapB = 2 * cc + 1, kyB = tapB / 3, kxB = tapB - kyB * 3;
            offB = (unsigned)((pm + kyB * PH + kxB) * 32 + (kg - 2) * 16);
          } else {
            offB = (unsigned)(zpix * 32 + (kg - 2) * 16);   // zeros
          }
          af[mi] = *(const short8*)(A0 + ((kg < 2) ? offA : offB));
        }
      } else {
        int hcc = cc - 5, tap = hcc >> 1, cgi = hcc & 1;
        int ky = tap / 3, kx = tap - ky * 3;
#pragma unroll
        for (int mi = 0; mi < 4; ++mi) {
          int pm = pix0 + mi * (2 * PH);
          af[mi] = *(const short8*)(A1 + (unsigned)((pm + ky * PH + kx) * 128 + cgi * 64 + kg * 16));
        }
      }
    } else {
      const char* srcb; int tap, half;
      if (cc < 18) { tap = cc >> 1; half = cc & 1; srcb = A0; }
      else         { int h = cc - 18; tap = h >> 1; half = h & 1; srcb = A1; }
      int ky = tap / 3, kx = tap - ky * 3;
#pragma unroll
      for (int mi = 0; mi < 4; ++mi) {
        int pm = pix0 + mi * (2 * PH);
        af[mi] = *(const short8*)(srcb + (unsigned)((pm + ky * PH + kx) * 128 + half * 64 + kg * 16));
      }
    }
  };

  f32x4 acc[4][4] = {};

  // prologue: W0,W1,W2 then af(0) — order pinned (vmcnt counts depend on it)
  ISSUE(0, 0); ISSUE(1, 1); ISSUE(2, 2);
  __builtin_amdgcn_sched_barrier(0);
  LOADA(0);
  __builtin_amdgcn_sched_barrier(0);

#pragma unroll
  for (int cc = 0; cc < NC; ++cc) {
    // exact wait for W(cc) landed: #vmem issued after W(cc)'s glls
    {
      const int N = (cc == 0) ? 8 : (cc == 1) ? 12
                  : 12 + ((cc + 1 < NC) ? 2 : 0) + ((cc + 2 < NC) ? 2 : 0);
      if      (N == 8)  asm volatile("s_waitcnt vmcnt(8)"  ::: "memory");
      else if (N == 12) asm volatile("s_waitcnt vmcnt(12)" ::: "memory");
      else if (N == 14) asm volatile("s_waitcnt vmcnt(14)" ::: "memory");
      else              asm volatile("s_waitcnt vmcnt(16)" ::: "memory");
    }
    __builtin_amdgcn_sched_barrier(0);
    __builtin_amdgcn_s_barrier();                    // raw: no compiler vmcnt drain
    __builtin_amdgcn_sched_barrier(0);

    // segment 2: bfv ds_reads + issue W(cc+3)
    const char* bufp = lds + (cc & 3) * 16384;
#pragma unroll
    for (int g = 0; g < 4; ++g)
      bfv[g] = *(const short8*)(bufp + (wn * 4 + g) * 1024 + l * 16);
    if (cc + 3 < NC) ISSUE(cc + 3, (cc + 3) & 3);    // overwrites buf (cc-1)&3: safe
    __builtin_amdgcn_sched_barrier(0);

    // segment 4: MFMAs consume af(cc), then af(cc+1) reloads the same regs
#pragma unroll
    for (int mi = 0; mi < 4; ++mi)
#pragma unroll
      for (int g = 0; g < 4; ++g)
        acc[mi][g] = __builtin_amdgcn_mfma_f32_16x16x32_bf16(
            af[mi], bfv[g], acc[mi][g], 0, 0, 0);
    if (cc + 1 < NC) LOADA(cc + 1);
    __builtin_amdgcn_sched_barrier(0);
  }

  // ---- gates (c/bias loaded after the counted-vmcnt pipeline)
  float bi[4];
#pragma unroll
  for (int g = 0; g < 4; ++g) bi[g] = bias[g * 64 + j];
  float cpre[4][4];
#pragma unroll
  for (int mi = 0; mi < 4; ++mi) {
#pragma unroll
    for (int rg = 0; rg < 4; ++rg) {
      if constexpr (T0C) { cpre[mi][rg] = 0.f; }
      else {
        int p = wm * 64 + mi * 16 + kg * 4 + rg;
        int y = by * 16 + (p >> 3), x = bx * 8 + (p & 7);
        cpre[mi][rg] = cbuf[((size_t)((b * Hv + y) * Wv) + x) * HID + j];
      }
    }
  }
#pragma unroll
  for (int mi = 0; mi < 4; ++mi) {
#pragma unroll
    for (int rg = 0; rg < 4; ++rg) {
      int p = wm * 64 + mi * 16 + kg * 4 + rg;       // C/D row = (lane>>4)*4 + reg
      int y = by * 16 + (p >> 3), x = bx * 8 + (p & 7);
      float zi = acc[mi][0][rg] + bi[0];
      float zf = acc[mi][1][rg] + bi[1];
      float zo = acc[mi][2][rg] + bi[2];
      float zg = acc[mi][3][rg] + bi[3];
      float cn = sigmoid_f(zf) * cpre[mi][rg] + sigmoid_f(zi) * tanh_f(zg);
      float hn = sigmoid_f(zo) * tanh_f(cn);
      size_t ci = ((size_t)((b * Hv + y) * Wv) + x) * HID + j;
      cbuf[ci] = cn;
      hout[((size_t)((b * PH + y + 1) * PH) + (x + 1)) * HID + j] = f2bf(hn);
      if (CELL == 1 && h1fin != nullptr) {
        h1fin[ci] = hn;
        c1fin[ci] = cn;
      }
    }
  }
}

// ---- fused dispatch D(t): cell1(t-1) || cell0(t) as block roles (independent).
// 512-thr blocks, 64KB LDS, launch_bounds(512,4) -> 2 blocks/CU in separate
// barrier domains.
template<int NC1, int NC0, bool LAST>
__global__ __launch_bounds__(512, 4)
void step_fused(const unsigned short* __restrict__ xbr, unsigned short* __restrict__ xbw,
                const unsigned short* __restrict__ h0r, unsigned short* __restrict__ h0w,
                const unsigned short* __restrict__ h1r, unsigned short* __restrict__ h1w,
                const unsigned short* __restrict__ w0r, const unsigned short* __restrict__ w1r,
                const float* __restrict__ b0, const float* __restrict__ b1,
                float* __restrict__ c0, float* __restrict__ c1,
                float* __restrict__ h1f, float* __restrict__ c1f,
                const float* __restrict__ enc, int tnext)
{
  extern __shared__ char lds[];
  const int tid = threadIdx.x;
  const int gid = blockIdx.x;
  int isC1, k;
  if constexpr (NC1 > 0 && NC0 > 0) { isC1 = gid & 1; k = gid >> 1; }
  else if constexpr (NC1 > 0)       { isC1 = 1; k = gid; }
  else                              { isC1 = 0; k = gid; }
  const int b = k >> 5, rem = k & 31;
  const int by = rem >> 3, bx = rem & 7;             // 16x8 px tile

  if constexpr (NC1 > 0) {
    if (isC1) {
      cell_run<1, NC1>((const char*)h0r, (const char*)h1r, (const char*)w1r, b1,
                       c1, h1w, LAST ? h1f : nullptr, LAST ? c1f : nullptr,
                       lds, b, by, bx, tid);
      return;
    }
  }
  if constexpr (NC0 > 0) {
    cell_run<0, NC0>((const char*)xbr, (const char*)h0r, (const char*)w0r, b0,
                     c0, h0w, nullptr, nullptr, lds, b, by, bx, tid);
    if (tnext >= 0) {                                // convert own 128-px tile of x(tnext)
      int pp = tid >> 2, q4 = tid & 3;
      int y = by * 16 + (pp >> 3), x = bx * 8 + (pp & 7);
      const float* s = enc + ((size_t)(b * Tv + tnext) * 4096 + (y * 64 + x)) * 16 + q4 * 4;
      float4 f = *(const float4*)s;
      unsigned short* d = xbw + ((size_t)((b * PH + y + 1) * PH) + (x + 1)) * 16 + q4 * 4;
      d[0] = f2bf(f.x); d[1] = f2bf(f.y); d[2] = f2bf(f.z); d[3] = f2bf(f.w);
    }
  }
}

extern "C" void kernel_launch(void* const* d_in, const int* in_sizes, int n_in,
                              void* d_out, int out_size, void* d_ws, size_t ws_size,
                              hipStream_t stream) {
  const float* enc = (const float*)d_in[0];
  const float* W0  = (const float*)d_in[1];
  const float* b0  = (const float*)d_in[2];
  const float* W1  = (const float*)d_in[3];
  const float* b1  = (const float*)d_in[4];

  float* out = (float*)d_out;
  const size_t NST = (size_t)Bv * Hv * Wv * HID;     // 2,097,152
  float* h1f = out;                                   // final h1 (fp32)
  float* c1  = out + NST;                             // c1 running state (fp32, in-place)

  char* ws = (char*)d_ws;
  const size_t SZ_C = NST * 4;                        // 8,388,608
  const size_t SZ_H = (size_t)Bv * PH * PH * HID * 2; // 4,460,544
  const size_t SZ_X = (size_t)Bv * PH * PH * 16 * 2;  // 1,115,136 (16ch rows)
  float*          c0  = (float*)ws;
  unsigned short* h0a = (unsigned short*)(ws + SZ_C);
  unsigned short* h0b = (unsigned short*)(ws + SZ_C + SZ_H);
  unsigned short* h1a = (unsigned short*)(ws + SZ_C + 2 * SZ_H);
  unsigned short* h1b = (unsigned short*)(ws + SZ_C + 3 * SZ_H);
  unsigned short* xb0 = (unsigned short*)(ws + SZ_C + 4 * SZ_H);
  unsigned short* xb1 = (unsigned short*)(ws + SZ_C + 4 * SZ_H + SZ_X);
  unsigned short* w0r = (unsigned short*)(ws + SZ_C + 4 * SZ_H + 2 * SZ_X);
  unsigned short* w1r = (unsigned short*)(ws + SZ_C + 4 * SZ_H + 2 * SZ_X + (size_t)23 * 16384);

  hipFuncSetAttribute((const void*)step_fused<0,5,false>,   hipFuncAttributeMaxDynamicSharedMemorySize, 65536);
  hipFuncSetAttribute((const void*)step_fused<18,23,false>, hipFuncAttributeMaxDynamicSharedMemorySize, 65536);
  hipFuncSetAttribute((const void*)step_fused<36,23,false>, hipFuncAttributeMaxDynamicSharedMemorySize, 65536);
  hipFuncSetAttribute((const void*)step_fused<36,0,true>,   hipFuncAttributeMaxDynamicSharedMemorySize, 65536);

  // zero only halos/pads (t=0 state handled by T0 prefix-chunks / c-skip)
  zero_init<<<805, 256, 0, stream>>>(h0a, h0b, h1a, h1b, xb0);
  relayout_w0<<<736, 256, 0, stream>>>(W0, w0r);
  relayout_w1<<<1152, 256, 0, stream>>>(W1, w1r);
  convert_x0<<<128, 256, 0, stream>>>(enc, xb0);

  const int LDSB = 65536;                            // 4 x 16KB (W only)
  // D(0): cell0(0) T0 (x chunks only); converts x(1) -> xb1
  step_fused<0,5,false><<<256, 512, LDSB, stream>>>(
      xb0, xb1, h0b, h0a, h1a, h1b, w0r, w1r, b0, b1, c0, c1,
      nullptr, nullptr, enc, 1);
  // D(t), t=1..15: cell1(t-1) || cell0(t) (+ convert x(t+1))
  for (int t = 1; t <= 15; ++t) {
    unsigned short* h0r = (t & 1) ? h0a : h0b;       // h0buf[(t-1)&1]
    unsigned short* h0w = (t & 1) ? h0b : h0a;       // h0buf[t&1]
    unsigned short* h1r = (t & 1) ? h1b : h1a;       // h1buf[t&1] (= h1(t-2))
    unsigned short* h1w = (t & 1) ? h1a : h1b;       // h1buf[(t-1)&1]
    unsigned short* xr  = (t & 1) ? xb1 : xb0;
    unsigned short* xw  = (t & 1) ? xb0 : xb1;
    int tn = (t + 1 <= 15) ? (t + 1) : -1;
    if (t == 1)
      step_fused<18,23,false><<<512, 512, LDSB, stream>>>(
          xr, xw, h0r, h0w, h1r, h1w, w0r, w1r, b0, b1, c0, c1,
          nullptr, nullptr, enc, tn);
    else
      step_fused<36,23,false><<<512, 512, LDSB, stream>>>(
          xr, xw, h0r, h0w, h1r, h1w, w0r, w1r, b0, b1, c0, c1,
          nullptr, nullptr, enc, tn);
  }
  // D(16): cell1(15) alone -> writes h1f/c1f
  step_fused<36,0,true><<<256, 512, LDSB, stream>>>(
      xb0, xb1, h0b, h0a, h1a, h1b, w0r, w1r, b0, b1, c0, c1,
      h1f, c1, enc, -1);
}

// Round 15
// 630.767 us; speedup vs baseline: 2.1041x; 2.1041x over previous
//
#include <hip/hip_runtime.h>
#include <hip/hip_bf16.h>

#define Bv 8
#define Tv 16
#define Hv 64
#define Wv 64
#define Cv 16
#define HID 64
#define PH 66   // spatially padded (1-px halo)

typedef short short8 __attribute__((ext_vector_type(8)));
typedef float f32x4 __attribute__((ext_vector_type(4)));
typedef unsigned short u16x8 __attribute__((ext_vector_type(8)));

__device__ __forceinline__ unsigned short f2bf(float x) {
  union { float f; unsigned int u; } v; v.f = x;
  unsigned int r = v.u + 0x7FFF + ((v.u >> 16) & 1);   // RNE
  return (unsigned short)(r >> 16);
}
__device__ __forceinline__ float sigmoid_f(float x) {
  return 1.f / (1.f + __expf(-x));
}
__device__ __forceinline__ float tanh_f(float x) {
  float e = __expf(2.f * x);
  return 1.f - 2.f / (e + 1.f);
}

// ---- W1 re-layout: fp32 [3,3,128,256] -> bf16 lane-contiguous chunks.
// Chunk cc (16KB): [wn(4)][g(4)][lane(64)][e(8)]; lane l=(kg*16+r) holds
// B[k=kg*8+e][col' = wn*64+g*16+r], orig col = g*64 + wn*16 + r.
__global__ void relayout_w1(const float* __restrict__ W1, unsigned short* __restrict__ out) {
  int o = blockIdx.x * 256 + threadIdx.x;            // 36*8192 = 294912
  if (o >= 36 * 8192) return;
  int cc = o >> 13, t = o & 8191;
  int wn = t >> 11, t2 = t & 2047;
  int g = t2 >> 9, t3 = t2 & 511;
  int l = t3 >> 3, e = t3 & 7;
  int kg = l >> 4, r = l & 15;
  int k = kg * 8 + e;
  int col = g * 64 + wn * 16 + r;
  int tap = cc >> 2, cgi = cc & 3;
  out[o] = f2bf(W1[(size_t)(tap * 128 + cgi * 32 + k) * 256 + col]);
}

// ---- W0 re-layout with x-tap pairing: 23 chunks.
// cc<4:  K = [tap 2cc ch0-15 | tap 2cc+1 ch0-15]
// cc==4: K = [tap 8 ch0-15 | zeros]
// cc>=5: h chunks: tap=(cc-5)>>1, cgi=(cc-5)&1, rows 16+cgi*32+k
__global__ void relayout_w0(const float* __restrict__ W0, unsigned short* __restrict__ out) {
  int o = blockIdx.x * 256 + threadIdx.x;            // 23*8192 = 188416
  if (o >= 23 * 8192) return;
  int cc = o >> 13, t = o & 8191;
  int wn = t >> 11, t2 = t & 2047;
  int g = t2 >> 9, t3 = t2 & 511;
  int l = t3 >> 3, e = t3 & 7;
  int kg = l >> 4, r = l & 15;
  int k = kg * 8 + e;
  int col = g * 64 + wn * 16 + r;
  float v = 0.f;
  if (cc < 4) {
    int tap = 2 * cc + (k >> 4);
    v = W0[(size_t)(tap * 80 + (k & 15)) * 256 + col];
  } else if (cc == 4) {
    if (k < 16) v = W0[(size_t)(8 * 80 + k) * 256 + col];
  } else {
    int hcc = cc - 5, tap = hcc >> 1, cgi = hcc & 1;
    v = W0[(size_t)(tap * 80 + 16 + cgi * 32 + k) * 256 + col];
  }
  out[o] = f2bf(v);
}

// ---- zero per call: both x buffers (16ch rows) + h halo rings
__global__ void zero_init(unsigned short* __restrict__ h0a, unsigned short* __restrict__ h0b,
                          unsigned short* __restrict__ h1a, unsigned short* __restrict__ h1b,
                          unsigned short* __restrict__ xb) {
  int idx = blockIdx.x * 256 + threadIdx.x;          // 16B chunks
  u16x8 z = {};
  const int XB_CH = (Bv * PH * PH * 16 * 2 * 2) / 16;  // two x buffers = 139392
  if (idx < XB_CH) { *(u16x8*)(xb + idx * 8) = z; return; }
  idx -= XB_CH;
  int bufi = idx / 16640;                            // 8 b x 260 px x 8 chunks
  if (bufi >= 4) return;
  int rem = idx - bufi * 16640;
  int b = rem / 2080, r2 = rem - b * 2080;
  int hp = r2 >> 3, c8 = r2 & 7;
  int y, x;
  if (hp < 66)       { y = 0;  x = hp; }
  else if (hp < 132) { y = 65; x = hp - 66; }
  else { int i2 = hp - 132; y = 1 + (i2 >> 1); x = (i2 & 1) * 65; }
  unsigned short* base = (bufi == 0) ? h0a : (bufi == 1) ? h0b : (bufi == 2) ? h1a : h1b;
  *(u16x8*)(base + ((size_t)((b * PH + y) * PH) + x) * 64 + c8 * 8) = z;
}

// ---- t=0 x conversion: enc fp32 -> padded bf16 [b][66][66][16]
__global__ void convert_x0(const float* __restrict__ enc, unsigned short* __restrict__ xb) {
  int idx = blockIdx.x * 256 + threadIdx.x;          // 32768
  int b = idx >> 12, pix = idx & 4095;
  int y = pix >> 6, x = pix & 63;
  const float* s = enc + ((size_t)(b * Tv + 0) * 4096 + pix) * 16;
  float4 f0 = *(const float4*)(s);
  float4 f1 = *(const float4*)(s + 4);
  float4 f2 = *(const float4*)(s + 8);
  float4 f3 = *(const float4*)(s + 12);
  u16x8 o0, o1;
  o0[0]=f2bf(f0.x); o0[1]=f2bf(f0.y); o0[2]=f2bf(f0.z); o0[3]=f2bf(f0.w);
  o0[4]=f2bf(f1.x); o0[5]=f2bf(f1.y); o0[6]=f2bf(f1.z); o0[7]=f2bf(f1.w);
  o1[0]=f2bf(f2.x); o1[1]=f2bf(f2.y); o1[2]=f2bf(f2.z); o1[3]=f2bf(f2.w);
  o1[4]=f2bf(f3.x); o1[5]=f2bf(f3.y); o1[6]=f2bf(f3.z); o1[7]=f2bf(f3.w);
  unsigned short* d = xb + ((size_t)((b * PH + y + 1) * PH) + (x + 1)) * 16;
  *(u16x8*)(d)     = o0;
  *(u16x8*)(d + 8) = o1;
}

// ---- one cell on a 128-px (16x8) x 256-gate-col tile: 8 waves (2wm x 4wn).
// Block-cooperative staging: per K=32 chunk A 8KB (wave stages frag w) +
// W 16KB (wave stages 2KB x2). 3 gll/wave/chunk. 3 LDS bufs x 24KB, 2 chunks
// in flight (vmcnt(3) steady, exact). ISSUE(cc+2) right after the barrier
// (all waves' ds_reads of that buf issued pre-barrier; gll lands >=200cy later).
// ds_read->MFMA ordering left to the compiler; setprio(1) wraps the MFMA
// cluster (T5: CU hosts mixed-role blocks -> scheduler favors MFMA waves).
// cell0 NC: 5 (T0) | 23; cell1 NC: 18 (T0) | 36.
template<int CELL, int NC>
__device__ __forceinline__ void cell_run(
    const char* __restrict__ A0, const char* __restrict__ A1,
    const char* __restrict__ Wr, const float* __restrict__ bias,
    float* __restrict__ cbuf, unsigned short* __restrict__ hout,
    float* __restrict__ h1fin, float* __restrict__ c1fin,
    char* lds, int b, int by, int bx, int tid)
{
  constexpr bool T0C = (CELL == 0) ? (NC == 5) : (NC == 18);
  const int l = tid & 63, w = tid >> 6;              // 8 waves
  const int wm = w >> 2, wn = w & 3;
  const int r = l & 15, kg = l >> 4;
  const int j = wn * 16 + r;

  int pixs;                                          // wave stages A px-frag w
  {
    int ps = w * 16 + r;
    int ys = by * 16 + (ps >> 3), xs = bx * 8 + (ps & 7);
    pixs = (b * PH + ys) * PH + xs;                  // tap(0,0) in padded coords
  }
  const int zpix = b * PH * PH;                      // zeroed halo corner of batch b

  auto ISSUE = [&](int cc, int buf) {
    char* dst = lds + buf * 24576;
    if constexpr (CELL == 0) {
      if (cc < 5) {
        // paired-tap x chunk: kg<2 -> tap 2cc, kg>=2 -> tap 2cc+1 (cc==4: zeros)
        int tapA = 2 * cc;
        int kyA = tapA / 3, kxA = tapA - kyA * 3;
        unsigned offA = (unsigned)((pixs + kyA * PH + kxA) * 32 + kg * 16);
        unsigned offB;
        if (cc < 4) {
          int tapB = tapA + 1;
          int kyB = tapB / 3, kxB = tapB - kyB * 3;
          offB = (unsigned)((pixs + kyB * PH + kxB) * 32 + (kg - 2) * 16);
        } else {
          offB = (unsigned)(zpix * 32 + (kg - 2) * 16);
        }
        unsigned aoff = (kg < 2) ? offA : offB;
        __builtin_amdgcn_global_load_lds((const unsigned int*)(A0 + aoff),
                                         (unsigned int*)(dst + w * 1024), 16, 0, 0);
      } else {
        int hcc = cc - 5, tap = hcc >> 1, cgi = hcc & 1;
        int ky = tap / 3, kx = tap - ky * 3;
        unsigned aoff = (unsigned)((pixs + ky * PH + kx) * 128 + cgi * 64 + kg * 16);
        __builtin_amdgcn_global_load_lds((const unsigned int*)(A1 + aoff),
                                         (unsigned int*)(dst + w * 1024), 16, 0, 0);
      }
    } else {
      int tap, cgi;
      if (T0C) { tap = cc >> 1; cgi = cc & 1; }
      else     { tap = cc >> 2; cgi = cc & 3; }
      int ky = tap / 3, kx = tap - ky * 3;
      const char* srcb = (cgi < 2) ? A0 : A1;
      unsigned aoff = (unsigned)((pixs + ky * PH + kx) * 128 + (cgi & 1) * 64 + kg * 16);
      __builtin_amdgcn_global_load_lds((const unsigned int*)(srcb + aoff),
                                       (unsigned int*)(dst + w * 1024), 16, 0, 0);
    }
    // W chunk index
    int wcc;
    if constexpr (CELL == 0) wcc = cc;
    else                     wcc = T0C ? ((cc >> 1) * 4 + (cc & 1)) : cc;
    const char* wp = Wr + (size_t)wcc * 16384 + (unsigned)(w * 2048 + l * 16);
    __builtin_amdgcn_global_load_lds((const unsigned int*)(wp),
                                     (unsigned int*)(dst + 8192 + w * 2048), 16, 0, 0);
    __builtin_amdgcn_global_load_lds((const unsigned int*)(wp + 1024),
                                     (unsigned int*)(dst + 8192 + w * 2048 + 1024), 16, 0, 0);
  };

  f32x4 acc[4][4] = {};
  short8 af[4], bfv[4];

  ISSUE(0, 0); ISSUE(1, 1);
#pragma unroll
  for (int cc = 0; cc < NC; ++cc) {
    if (cc <= NC - 2) { asm volatile("s_waitcnt vmcnt(3)" ::: "memory"); }
    else              { asm volatile("s_waitcnt vmcnt(0)" ::: "memory"); }
    __builtin_amdgcn_sched_barrier(0);
    __builtin_amdgcn_s_barrier();                    // raw: no compiler vmcnt drain
    __builtin_amdgcn_sched_barrier(0);

    if (cc + 2 < NC) ISSUE(cc + 2, (cc + 2) % 3);    // overwrites buf (cc-1)%3: safe

    const char* bufp = lds + (cc % 3) * 24576;
#pragma unroll
    for (int mi = 0; mi < 4; ++mi)
      af[mi] = *(const short8*)(bufp + (wm * 4 + mi) * 1024 + l * 16);
#pragma unroll
    for (int g = 0; g < 4; ++g)
      bfv[g] = *(const short8*)(bufp + 8192 + (wn * 4 + g) * 1024 + l * 16);

    __builtin_amdgcn_s_setprio(1);
#pragma unroll
    for (int mi = 0; mi < 4; ++mi)
#pragma unroll
      for (int g = 0; g < 4; ++g)
        acc[mi][g] = __builtin_amdgcn_mfma_f32_16x16x32_bf16(
            af[mi], bfv[g], acc[mi][g], 0, 0, 0);
    __builtin_amdgcn_s_setprio(0);
  }

  // ---- gates (c/bias loaded after the counted-vmcnt pipeline)
  float bi[4];
#pragma unroll
  for (int g = 0; g < 4; ++g) bi[g] = bias[g * 64 + j];
  float cpre[4][4];
#pragma unroll
  for (int mi = 0; mi < 4; ++mi) {
#pragma unroll
    for (int rg = 0; rg < 4; ++rg) {
      if constexpr (T0C) { cpre[mi][rg] = 0.f; }
      else {
        int p = wm * 64 + mi * 16 + kg * 4 + rg;
        int y = by * 16 + (p >> 3), x = bx * 8 + (p & 7);
        cpre[mi][rg] = cbuf[((size_t)((b * Hv + y) * Wv) + x) * HID + j];
      }
    }
  }
#pragma unroll
  for (int mi = 0; mi < 4; ++mi) {
#pragma unroll
    for (int rg = 0; rg < 4; ++rg) {
      int p = wm * 64 + mi * 16 + kg * 4 + rg;       // C/D row = (lane>>4)*4 + reg
      int y = by * 16 + (p >> 3), x = bx * 8 + (p & 7);
      float zi = acc[mi][0][rg] + bi[0];
      float zf = acc[mi][1][rg] + bi[1];
      float zo = acc[mi][2][rg] + bi[2];
      float zg = acc[mi][3][rg] + bi[3];
      float cn = sigmoid_f(zf) * cpre[mi][rg] + sigmoid_f(zi) * tanh_f(zg);
      float hn = sigmoid_f(zo) * tanh_f(cn);
      size_t ci = ((size_t)((b * Hv + y) * Wv) + x) * HID + j;
      cbuf[ci] = cn;
      hout[((size_t)((b * PH + y + 1) * PH) + (x + 1)) * HID + j] = f2bf(hn);
      if (CELL == 1 && h1fin != nullptr) {
        h1fin[ci] = hn;
        c1fin[ci] = cn;
      }
    }
  }
}

// ---- fused dispatch D(t): cell1(t-1) || cell0(t) as block roles (independent).
// 512-thr blocks, 72KB LDS, launch_bounds(512,4) -> 2 blocks/CU.
// ROLE SPLIT BY gid<256 (not gid&1): HW assigns gid g and g+256 to the SAME
// CU, so this guarantees each CU hosts ONE cell1 (36 chunks) + ONE cell0 (23)
// block -> balanced 59 chunks/CU, cross-role stall covering.
template<int NC1, int NC0, bool LAST>
__global__ __launch_bounds__(512, 4)
void step_fused(const unsigned short* __restrict__ xbr, unsigned short* __restrict__ xbw,
                const unsigned short* __restrict__ h0r, unsigned short* __restrict__ h0w,
                const unsigned short* __restrict__ h1r, unsigned short* __restrict__ h1w,
                const unsigned short* __restrict__ w0r, const unsigned short* __restrict__ w1r,
                const float* __restrict__ b0, const float* __restrict__ b1,
                float* __restrict__ c0, float* __restrict__ c1,
                float* __restrict__ h1f, float* __restrict__ c1f,
                const float* __restrict__ enc, int tnext)
{
  extern __shared__ char lds[];
  const int tid = threadIdx.x;
  const int gid = blockIdx.x;
  int isC1, k;
  if constexpr (NC1 > 0 && NC0 > 0) { isC1 = (gid < 256) ? 1 : 0; k = gid & 255; }
  else if constexpr (NC1 > 0)       { isC1 = 1; k = gid; }
  else                              { isC1 = 0; k = gid; }
  const int b = k >> 5, rem = k & 31;
  const int by = rem >> 3, bx = rem & 7;             // 16x8 px tile

  if constexpr (NC1 > 0) {
    if (isC1) {
      cell_run<1, NC1>((const char*)h0r, (const char*)h1r, (const char*)w1r, b1,
                       c1, h1w, LAST ? h1f : nullptr, LAST ? c1f : nullptr,
                       lds, b, by, bx, tid);
      return;
    }
  }
  if constexpr (NC0 > 0) {
    cell_run<0, NC0>((const char*)xbr, (const char*)h0r, (const char*)w0r, b0,
                     c0, h0w, nullptr, nullptr, lds, b, by, bx, tid);
    if (tnext >= 0) {                                // convert own 128-px tile of x(tnext)
      int pp = tid >> 2, q4 = tid & 3;
      int y = by * 16 + (pp >> 3), x = bx * 8 + (pp & 7);
      const float* s = enc + ((size_t)(b * Tv + tnext) * 4096 + (y * 64 + x)) * 16 + q4 * 4;
      float4 f = *(const float4*)s;
      unsigned short* d = xbw + ((size_t)((b * PH + y + 1) * PH) + (x + 1)) * 16 + q4 * 4;
      d[0] = f2bf(f.x); d[1] = f2bf(f.y); d[2] = f2bf(f.z); d[3] = f2bf(f.w);
    }
  }
}

extern "C" void kernel_launch(void* const* d_in, const int* in_sizes, int n_in,
                              void* d_out, int out_size, void* d_ws, size_t ws_size,
                              hipStream_t stream) {
  const float* enc = (const float*)d_in[0];
  const float* W0  = (const float*)d_in[1];
  const float* b0  = (const float*)d_in[2];
  const float* W1  = (const float*)d_in[3];
  const float* b1  = (const float*)d_in[4];

  float* out = (float*)d_out;
  const size_t NST = (size_t)Bv * Hv * Wv * HID;     // 2,097,152
  float* h1f = out;                                   // final h1 (fp32)
  float* c1  = out + NST;                             // c1 running state (fp32, in-place)

  char* ws = (char*)d_ws;
  const size_t SZ_C = NST * 4;                        // 8,388,608
  const size_t SZ_H = (size_t)Bv * PH * PH * HID * 2; // 4,460,544
  const size_t SZ_X = (size_t)Bv * PH * PH * 16 * 2;  // 1,115,136 (16ch rows)
  float*          c0  = (float*)ws;
  unsigned short* h0a = (unsigned short*)(ws + SZ_C);
  unsigned short* h0b = (unsigned short*)(ws + SZ_C + SZ_H);
  unsigned short* h1a = (unsigned short*)(ws + SZ_C + 2 * SZ_H);
  unsigned short* h1b = (unsigned short*)(ws + SZ_C + 3 * SZ_H);
  unsigned short* xb0 = (unsigned short*)(ws + SZ_C + 4 * SZ_H);
  unsigned short* xb1 = (unsigned short*)(ws + SZ_C + 4 * SZ_H + SZ_X);
  unsigned short* w0r = (unsigned short*)(ws + SZ_C + 4 * SZ_H + 2 * SZ_X);
  unsigned short* w1r = (unsigned short*)(ws + SZ_C + 4 * SZ_H + 2 * SZ_X + (size_t)23 * 16384);

  hipFuncSetAttribute((const void*)step_fused<0,5,false>,   hipFuncAttributeMaxDynamicSharedMemorySize, 73728);
  hipFuncSetAttribute((const void*)step_fused<18,23,false>, hipFuncAttributeMaxDynamicSharedMemorySize, 73728);
  hipFuncSetAttribute((const void*)step_fused<36,23,false>, hipFuncAttributeMaxDynamicSharedMemorySize, 73728);
  hipFuncSetAttribute((const void*)step_fused<36,0,true>,   hipFuncAttributeMaxDynamicSharedMemorySize, 73728);

  // zero only halos/pads (t=0 state handled by T0 chunk-skip / c-skip)
  zero_init<<<805, 256, 0, stream>>>(h0a, h0b, h1a, h1b, xb0);
  relayout_w0<<<736, 256, 0, stream>>>(W0, w0r);
  relayout_w1<<<1152, 256, 0, stream>>>(W1, w1r);
  convert_x0<<<128, 256, 0, stream>>>(enc, xb0);

  const int LDSB = 73728;                            // 3 x 24KB
  // D(0): cell0(0) T0 (x chunks only); converts x(1) -> xb1
  step_fused<0,5,false><<<256, 512, LDSB, stream>>>(
      xb0, xb1, h0b, h0a, h1a, h1b, w0r, w1r, b0, b1, c0, c1,
      nullptr, nullptr, enc, 1);
  // D(t), t=1..15: cell1(t-1) || cell0(t) (+ convert x(t+1))
  for (int t = 1; t <= 15; ++t) {
    unsigned short* h0r = (t & 1) ? h0a : h0b;       // h0buf[(t-1)&1]
    unsigned short* h0w = (t & 1) ? h0b : h0a;       // h0buf[t&1]
    unsigned short* h1r = (t & 1) ? h1b : h1a;       // h1buf[t&1] (= h1(t-2))
    unsigned short* h1w = (t & 1) ? h1a : h1b;       // h1buf[(t-1)&1]
    unsigned short* xr  = (t & 1) ? xb1 : xb0;
    unsigned short* xw  = (t & 1) ? xb0 : xb1;
    int tn = (t + 1 <= 15) ? (t + 1) : -1;
    if (t == 1)
      step_fused<18,23,false><<<512, 512, LDSB, stream>>>(
          xr, xw, h0r, h0w, h1r, h1w, w0r, w1r, b0, b1, c0, c1,
          nullptr, nullptr, enc, tn);
    else
      step_fused<36,23,false><<<512, 512, LDSB, stream>>>(
          xr, xw, h0r, h0w, h1r, h1w, w0r, w1r, b0, b1, c0, c1,
          nullptr, nullptr, enc, tn);
  }
  // D(16): cell1(15) alone -> writes h1f/c1f
  step_fused<36,0,true><<<256, 512, LDSB, stream>>>(
      xb0, xb1, h0b, h0a, h1a, h1b, w0r, w1r, b0, b1, c0, c1,
      h1f, c1, enc, -1);
}

// Round 18
// 622.542 us; speedup vs baseline: 2.1319x; 1.0132x over previous
//
#include <hip/hip_runtime.h>
#include <hip/hip_bf16.h>

#define Bv 8
#define Tv 16
#define Hv 64
#define Wv 64
#define Cv 16
#define HID 64
#define PH 66   // spatially padded (1-px halo)

typedef short short8 __attribute__((ext_vector_type(8)));
typedef float f32x4 __attribute__((ext_vector_type(4)));
typedef unsigned short u16x8 __attribute__((ext_vector_type(8)));

__device__ __forceinline__ unsigned short f2bf(float x) {
  union { float f; unsigned int u; } v; v.f = x;
  unsigned int r = v.u + 0x7FFF + ((v.u >> 16) & 1);   // RNE
  return (unsigned short)(r >> 16);
}
__device__ __forceinline__ float sigmoid_f(float x) {
  return 1.f / (1.f + __expf(-x));
}
__device__ __forceinline__ float tanh_f(float x) {
  float e = __expf(2.f * x);
  return 1.f - 2.f / (e + 1.f);
}

// ---- fused one-shot init, ALL REGIONS WRITE-DISJOINT (r16/r17 bug: zeroing
// x interiors raced with the conv region writing x(0) interiors; r15's
// separate launches serialized them). Now: zero only x HALO RINGS + h halo
// rings; x interiors are written by conv (t=0) / step tails (t>=1) before
// any read. Block ranges: [0,293) zero, [293,1029) w0, [1029,2181) w1,
// [2181,2309) conv.
__global__ void init_all(const float* __restrict__ enc,
                         const float* __restrict__ W0, const float* __restrict__ W1,
                         unsigned short* __restrict__ h0a, unsigned short* __restrict__ h0b,
                         unsigned short* __restrict__ h1a, unsigned short* __restrict__ h1b,
                         unsigned short* __restrict__ xb0, unsigned short* __restrict__ xb1,
                         unsigned short* __restrict__ w0r, unsigned short* __restrict__ w1r)
{
  const int gb = blockIdx.x, tid = threadIdx.x;
  if (gb < 293) {
    int idx = gb * 256 + tid;
    u16x8 z = {};
    // x halo rings: 2 bufs x 8 b x 260 ring px x 2 chunks(16B) = 8320
    if (idx < 8320) {
      int bufi = idx / 4160, rem = idx - bufi * 4160;
      int b = rem / 520, r2 = rem - b * 520;
      int hp = r2 >> 1, c8 = r2 & 1;
      int y, x;
      if (hp < 66)       { y = 0;  x = hp; }
      else if (hp < 132) { y = 65; x = hp - 66; }
      else { int i2 = hp - 132; y = 1 + (i2 >> 1); x = (i2 & 1) * 65; }
      unsigned short* base = bufi ? xb1 : xb0;
      *(u16x8*)(base + ((size_t)((b * PH + y) * PH) + x) * 16 + c8 * 8) = z;
      return;
    }
    idx -= 8320;
    // h halo rings: 4 bufs x 8 b x 260 px x 8 chunks = 66560
    int bufi = idx / 16640;
    if (bufi >= 4) return;
    int rem = idx - bufi * 16640;
    int b = rem / 2080, r2 = rem - b * 2080;
    int hp = r2 >> 3, c8 = r2 & 7;
    int y, x;
    if (hp < 66)       { y = 0;  x = hp; }
    else if (hp < 132) { y = 65; x = hp - 66; }
    else { int i2 = hp - 132; y = 1 + (i2 >> 1); x = (i2 & 1) * 65; }
    unsigned short* base = (bufi == 0) ? h0a : (bufi == 1) ? h0b : (bufi == 2) ? h1a : h1b;
    *(u16x8*)(base + ((size_t)((b * PH + y) * PH) + x) * 64 + c8 * 8) = z;
  } else if (gb < 1029) {
    // W0 re-layout with x-tap pairing: 23 chunks.
    int o = (gb - 293) * 256 + tid;
    if (o >= 23 * 8192) return;
    int cc = o >> 13, t = o & 8191;
    int wn = t >> 11, t2 = t & 2047;
    int g = t2 >> 9, t3 = t2 & 511;
    int l = t3 >> 3, e = t3 & 7;
    int kg = l >> 4, r = l & 15;
    int k = kg * 8 + e;
    int col = g * 64 + wn * 16 + r;
    float v = 0.f;
    if (cc < 4) {
      int tap = 2 * cc + (k >> 4);
      v = W0[(size_t)(tap * 80 + (k & 15)) * 256 + col];
    } else if (cc == 4) {
      if (k < 16) v = W0[(size_t)(8 * 80 + k) * 256 + col];
    } else {
      int hcc = cc - 5, tap = hcc >> 1, cgi = hcc & 1;
      v = W0[(size_t)(tap * 80 + 16 + cgi * 32 + k) * 256 + col];
    }
    w0r[o] = f2bf(v);
  } else if (gb < 2181) {
    // W1 re-layout: 36 chunks [tap(9)][cgi(4)] of K=32.
    int o = (gb - 1029) * 256 + tid;
    if (o >= 36 * 8192) return;
    int cc = o >> 13, t = o & 8191;
    int wn = t >> 11, t2 = t & 2047;
    int g = t2 >> 9, t3 = t2 & 511;
    int l = t3 >> 3, e = t3 & 7;
    int kg = l >> 4, r = l & 15;
    int k = kg * 8 + e;
    int col = g * 64 + wn * 16 + r;
    int tap = cc >> 2, cgi = cc & 3;
    w1r[o] = f2bf(W1[(size_t)(tap * 128 + cgi * 32 + k) * 256 + col]);
  } else {
    // x(0) convert: enc fp32 -> padded bf16 [b][66][66][16] (interior only)
    int idx = (gb - 2181) * 256 + tid;                 // 32768
    int b = idx >> 12, pix = idx & 4095;
    int y = pix >> 6, x = pix & 63;
    const float* s = enc + ((size_t)(b * Tv + 0) * 4096 + pix) * 16;
    float4 f0 = *(const float4*)(s);
    float4 f1 = *(const float4*)(s + 4);
    float4 f2 = *(const float4*)(s + 8);
    float4 f3 = *(const float4*)(s + 12);
    u16x8 o0, o1;
    o0[0]=f2bf(f0.x); o0[1]=f2bf(f0.y); o0[2]=f2bf(f0.z); o0[3]=f2bf(f0.w);
    o0[4]=f2bf(f1.x); o0[5]=f2bf(f1.y); o0[6]=f2bf(f1.z); o0[7]=f2bf(f1.w);
    o1[0]=f2bf(f2.x); o1[1]=f2bf(f2.y); o1[2]=f2bf(f2.z); o1[3]=f2bf(f2.w);
    o1[4]=f2bf(f3.x); o1[5]=f2bf(f3.y); o1[6]=f2bf(f3.z); o1[7]=f2bf(f3.w);
    unsigned short* d = xb0 + ((size_t)((b * PH + y + 1) * PH) + (x + 1)) * 16;
    *(u16x8*)(d)     = o0;
    *(u16x8*)(d + 8) = o1;
  }
}

// ---- one cell on a 128-px (16x8) x 256-gate-col tile: 8 waves (2wm x 4wn).
// r15-verbatim pipeline (PASSED at 630.8us): block-cooperative staging, per
// K=32 chunk A 8KB (wave stages frag w) + W 16KB (wave stages 2KB x2), 3 gll
// per wave per chunk. 3 combined LDS bufs x 24KB, 2 chunks in flight
// (vmcnt(3) steady, exact). ISSUE(cc+2) right after the barrier. ds_read->MFMA
// ordering left to compiler; setprio(1) around the MFMA cluster (T5).
// cell0 NC: 5 (T0) | 23; cell1 NC: 18 (T0) | 36.
template<int CELL, int NC>
__device__ __forceinline__ void cell_run(
    const char* __restrict__ A0, const char* __restrict__ A1,
    const char* __restrict__ Wr, const float* __restrict__ bias,
    float* __restrict__ cbuf, unsigned short* __restrict__ hout,
    float* __restrict__ h1fin, float* __restrict__ c1fin,
    char* lds, int b, int by, int bx, int tid)
{
  constexpr bool T0C = (CELL == 0) ? (NC == 5) : (NC == 18);
  const int l = tid & 63, w = tid >> 6;              // 8 waves
  const int wm = w >> 2, wn = w & 3;
  const int r = l & 15, kg = l >> 4;
  const int j = wn * 16 + r;

  int pixs;                                          // wave stages A px-frag w
  {
    int ps = w * 16 + r;
    int ys = by * 16 + (ps >> 3), xs = bx * 8 + (ps & 7);
    pixs = (b * PH + ys) * PH + xs;                  // tap(0,0) in padded coords
  }
  const int zpix = b * PH * PH;                      // zeroed halo corner of batch b

  auto ISSUE = [&](int cc, int buf) {
    char* dst = lds + buf * 24576;
    if constexpr (CELL == 0) {
      if (cc < 5) {
        // paired-tap x chunk: kg<2 -> tap 2cc, kg>=2 -> tap 2cc+1 (cc==4: zeros)
        int tapA = 2 * cc;
        int kyA = tapA / 3, kxA = tapA - kyA * 3;
        unsigned offA = (unsigned)((pixs + kyA * PH + kxA) * 32 + kg * 16);
        unsigned offB;
        if (cc < 4) {
          int tapB = tapA + 1;
          int kyB = tapB / 3, kxB = tapB - kyB * 3;
          offB = (unsigned)((pixs + kyB * PH + kxB) * 32 + (kg - 2) * 16);
        } else {
          offB = (unsigned)(zpix * 32 + (kg - 2) * 16);
        }
        unsigned aoff = (kg < 2) ? offA : offB;
        __builtin_amdgcn_global_load_lds((const unsigned int*)(A0 + aoff),
                                         (unsigned int*)(dst + w * 1024), 16, 0, 0);
      } else {
        int hcc = cc - 5, tap = hcc >> 1, cgi = hcc & 1;
        int ky = tap / 3, kx = tap - ky * 3;
        unsigned aoff = (unsigned)((pixs + ky * PH + kx) * 128 + cgi * 64 + kg * 16);
        __builtin_amdgcn_global_load_lds((const unsigned int*)(A1 + aoff),
                                         (unsigned int*)(dst + w * 1024), 16, 0, 0);
      }
    } else {
      int tap, cgi;
      if (T0C) { tap = cc >> 1; cgi = cc & 1; }
      else     { tap = cc >> 2; cgi = cc & 3; }
      int ky = tap / 3, kx = tap - ky * 3;
      const char* srcb = (cgi < 2) ? A0 : A1;
      unsigned aoff = (unsigned)((pixs + ky * PH + kx) * 128 + (cgi & 1) * 64 + kg * 16);
      __builtin_amdgcn_global_load_lds((const unsigned int*)(srcb + aoff),
                                       (unsigned int*)(dst + w * 1024), 16, 0, 0);
    }
    // W chunk index
    int wcc;
    if constexpr (CELL == 0) wcc = cc;
    else                     wcc = T0C ? ((cc >> 1) * 4 + (cc & 1)) : cc;
    const char* wp = Wr + (size_t)wcc * 16384 + (unsigned)(w * 2048 + l * 16);
    __builtin_amdgcn_global_load_lds((const unsigned int*)(wp),
                                     (unsigned int*)(dst + 8192 + w * 2048), 16, 0, 0);
    __builtin_amdgcn_global_load_lds((const unsigned int*)(wp + 1024),
                                     (unsigned int*)(dst + 8192 + w * 2048 + 1024), 16, 0, 0);
  };

  f32x4 acc[4][4] = {};
  short8 af[4], bfv[4];

  ISSUE(0, 0); ISSUE(1, 1);
#pragma unroll
  for (int cc = 0; cc < NC; ++cc) {
    if (cc <= NC - 2) { asm volatile("s_waitcnt vmcnt(3)" ::: "memory"); }
    else              { asm volatile("s_waitcnt vmcnt(0)" ::: "memory"); }
    __builtin_amdgcn_sched_barrier(0);
    __builtin_amdgcn_s_barrier();                    // raw: no compiler vmcnt drain
    __builtin_amdgcn_sched_barrier(0);

    if (cc + 2 < NC) ISSUE(cc + 2, (cc + 2) % 3);    // overwrites buf (cc-1)%3: safe

    const char* bufp = lds + (cc % 3) * 24576;
#pragma unroll
    for (int mi = 0; mi < 4; ++mi)
      af[mi] = *(const short8*)(bufp + (wm * 4 + mi) * 1024 + l * 16);
#pragma unroll
    for (int g = 0; g < 4; ++g)
      bfv[g] = *(const short8*)(bufp + 8192 + (wn * 4 + g) * 1024 + l * 16);

    __builtin_amdgcn_s_setprio(1);
#pragma unroll
    for (int mi = 0; mi < 4; ++mi)
#pragma unroll
      for (int g = 0; g < 4; ++g)
        acc[mi][g] = __builtin_amdgcn_mfma_f32_16x16x32_bf16(
            af[mi], bfv[g], acc[mi][g], 0, 0, 0);
    __builtin_amdgcn_s_setprio(0);
  }

  // ---- gates (c/bias loaded after the counted-vmcnt pipeline)
  float bi[4];
#pragma unroll
  for (int g = 0; g < 4; ++g) bi[g] = bias[g * 64 + j];
  float cpre[4][4];
#pragma unroll
  for (int mi = 0; mi < 4; ++mi) {
#pragma unroll
    for (int rg = 0; rg < 4; ++rg) {
      if constexpr (T0C) { cpre[mi][rg] = 0.f; }
      else {
        int p = wm * 64 + mi * 16 + kg * 4 + rg;
        int y = by * 16 + (p >> 3), x = bx * 8 + (p & 7);
        cpre[mi][rg] = cbuf[((size_t)((b * Hv + y) * Wv) + x) * HID + j];
      }
    }
  }
#pragma unroll
  for (int mi = 0; mi < 4; ++mi) {
#pragma unroll
    for (int rg = 0; rg < 4; ++rg) {
      int p = wm * 64 + mi * 16 + kg * 4 + rg;       // C/D row = (lane>>4)*4 + reg
      int y = by * 16 + (p >> 3), x = bx * 8 + (p & 7);
      float zi = acc[mi][0][rg] + bi[0];
      float zf = acc[mi][1][rg] + bi[1];
      float zo = acc[mi][2][rg] + bi[2];
      float zg = acc[mi][3][rg] + bi[3];
      float cn = sigmoid_f(zf) * cpre[mi][rg] + sigmoid_f(zi) * tanh_f(zg);
      float hn = sigmoid_f(zo) * tanh_f(cn);
      size_t ci = ((size_t)((b * Hv + y) * Wv) + x) * HID + j;
      cbuf[ci] = cn;
      hout[((size_t)((b * PH + y + 1) * PH) + (x + 1)) * HID + j] = f2bf(hn);
      if (CELL == 1 && h1fin != nullptr) {
        h1fin[ci] = hn;
        c1fin[ci] = cn;
      }
    }
  }
}

// ---- fused dispatch D(t): cell1(t-1) || cell0(t) as block roles (independent).
// 512-thr blocks, 72KB LDS, launch_bounds(512,4). Role split by gid<256:
// HW assigns gid g and g+256 to the same CU -> each CU hosts one cell1 (36
// chunks) + one cell0 (23 chunks) block.
template<int NC1, int NC0, bool LAST>
__global__ __launch_bounds__(512, 4)
void step_fused(const unsigned short* __restrict__ xbr, unsigned short* __restrict__ xbw,
                const unsigned short* __restrict__ h0r, unsigned short* __restrict__ h0w,
                const unsigned short* __restrict__ h1r, unsigned short* __restrict__ h1w,
                const unsigned short* __restrict__ w0r, const unsigned short* __restrict__ w1r,
                const float* __restrict__ b0, const float* __restrict__ b1,
                float* __restrict__ c0, float* __restrict__ c1,
                float* __restrict__ h1f, float* __restrict__ c1f,
                const float* __restrict__ enc, int tnext)
{
  extern __shared__ char lds[];
  const int tid = threadIdx.x;
  const int gid = blockIdx.x;
  int isC1, k;
  if constexpr (NC1 > 0 && NC0 > 0) { isC1 = (gid < 256) ? 1 : 0; k = gid & 255; }
  else if constexpr (NC1 > 0)       { isC1 = 1; k = gid; }
  else                              { isC1 = 0; k = gid; }
  const int b = k >> 5, rem = k & 31;
  const int by = rem >> 3, bx = rem & 7;             // 16x8 px tile

  if constexpr (NC1 > 0) {
    if (isC1) {
      cell_run<1, NC1>((const char*)h0r, (const char*)h1r, (const char*)w1r, b1,
                       c1, h1w, LAST ? h1f : nullptr, LAST ? c1f : nullptr,
                       lds, b, by, bx, tid);
      return;
    }
  }
  if constexpr (NC0 > 0) {
    cell_run<0, NC0>((const char*)xbr, (const char*)h0r, (const char*)w0r, b0,
                     c0, h0w, nullptr, nullptr, lds, b, by, bx, tid);
    if (tnext >= 0) {                                // convert own 128-px tile of x(tnext)
      int pp = tid >> 2, q4 = tid & 3;
      int y = by * 16 + (pp >> 3), x = bx * 8 + (pp & 7);
      const float* s = enc + ((size_t)(b * Tv + tnext) * 4096 + (y * 64 + x)) * 16 + q4 * 4;
      float4 f = *(const float4*)s;
      unsigned short* d = xbw + ((size_t)((b * PH + y + 1) * PH) + (x + 1)) * 16 + q4 * 4;
      d[0] = f2bf(f.x); d[1] = f2bf(f.y); d[2] = f2bf(f.z); d[3] = f2bf(f.w);
    }
  }
}

extern "C" void kernel_launch(void* const* d_in, const int* in_sizes, int n_in,
                              void* d_out, int out_size, void* d_ws, size_t ws_size,
                              hipStream_t stream) {
  const float* enc = (const float*)d_in[0];
  const float* W0  = (const float*)d_in[1];
  const float* b0  = (const float*)d_in[2];
  const float* W1  = (const float*)d_in[3];
  const float* b1  = (const float*)d_in[4];

  float* out = (float*)d_out;
  const size_t NST = (size_t)Bv * Hv * Wv * HID;     // 2,097,152
  float* h1f = out;                                   // final h1 (fp32)
  float* c1  = out + NST;                             // c1 running state (fp32, in-place)

  char* ws = (char*)d_ws;
  const size_t SZ_C = NST * 4;                        // 8,388,608
  const size_t SZ_H = (size_t)Bv * PH * PH * HID * 2; // 4,460,544
  const size_t SZ_X = (size_t)Bv * PH * PH * 16 * 2;  // 1,115,136 (16ch rows)
  float*          c0  = (float*)ws;
  unsigned short* h0a = (unsigned short*)(ws + SZ_C);
  unsigned short* h0b = (unsigned short*)(ws + SZ_C + SZ_H);
  unsigned short* h1a = (unsigned short*)(ws + SZ_C + 2 * SZ_H);
  unsigned short* h1b = (unsigned short*)(ws + SZ_C + 3 * SZ_H);
  unsigned short* xb0 = (unsigned short*)(ws + SZ_C + 4 * SZ_H);
  unsigned short* xb1 = (unsigned short*)(ws + SZ_C + 4 * SZ_H + SZ_X);
  unsigned short* w0r = (unsigned short*)(ws + SZ_C + 4 * SZ_H + 2 * SZ_X);
  unsigned short* w1r = (unsigned short*)(ws + SZ_C + 4 * SZ_H + 2 * SZ_X + (size_t)23 * 16384);

  hipFuncSetAttribute((const void*)step_fused<0,5,false>,   hipFuncAttributeMaxDynamicSharedMemorySize, 73728);
  hipFuncSetAttribute((const void*)step_fused<18,23,false>, hipFuncAttributeMaxDynamicSharedMemorySize, 73728);
  hipFuncSetAttribute((const void*)step_fused<36,23,false>, hipFuncAttributeMaxDynamicSharedMemorySize, 73728);
  hipFuncSetAttribute((const void*)step_fused<36,0,true>,   hipFuncAttributeMaxDynamicSharedMemorySize, 73728);

  // single fused init (write-disjoint regions): x/h halo zeroing + W
  // re-layouts + x(0) interior convert
  init_all<<<2309, 256, 0, stream>>>(enc, W0, W1, h0a, h0b, h1a, h1b,
                                     xb0, xb1, w0r, w1r);

  const int LDSB = 73728;                            // 3 x 24KB
  // D(0): cell0(0) T0 (x chunks only); converts x(1) -> xb1
  step_fused<0,5,false><<<256, 512, LDSB, stream>>>(
      xb0, xb1, h0b, h0a, h1a, h1b, w0r, w1r, b0, b1, c0, c1,
      nullptr, nullptr, enc, 1);
  // D(t), t=1..15: cell1(t-1) || cell0(t) (+ convert x(t+1))
  for (int t = 1; t <= 15; ++t) {
    unsigned short* h0r = (t & 1) ? h0a : h0b;       // h0buf[(t-1)&1]
    unsigned short* h0w = (t & 1) ? h0b : h0a;       // h0buf[t&1]
    unsigned short* h1r = (t & 1) ? h1b : h1a;       // h1buf[t&1] (= h1(t-2))
    unsigned short* h1w = (t & 1) ? h1a : h1b;       // h1buf[(t-1)&1]
    unsigned short* xr  = (t & 1) ? xb1 : xb0;
    unsigned short* xw  = (t & 1) ? xb0 : xb1;
    int tn = (t + 1 <= 15) ? (t + 1) : -1;
    if (t == 1)
      step_fused<18,23,false><<<512, 512, LDSB, stream>>>(
          xr, xw, h0r, h0w, h1r, h1w, w0r, w1r, b0, b1, c0, c1,
          nullptr, nullptr, enc, tn);
    else
      step_fused<36,23,false><<<512, 512, LDSB, stream>>>(
          xr, xw, h0r, h0w, h1r, h1w, w0r, w1r, b0, b1, c0, c1,
          nullptr, nullptr, enc, tn);
  }
  // D(16): cell1(15) alone -> writes h1f/c1f
  step_fused<36,0,true><<<256, 512, LDSB, stream>>>(
      xb0, xb1, h0b, h0a, h1a, h1b, w0r, w1r, b0, b1, c0, c1,
      h1f, c1, enc, -1);
}

// Round 19
// 602.903 us; speedup vs baseline: 2.2013x; 1.0326x over previous
//
#include <hip/hip_runtime.h>
#include <hip/hip_bf16.h>

#define Bv 8
#define Tv 16
#define Hv 64
#define Wv 64
#define Cv 16
#define HID 64
#define PH 66   // spatially padded (1-px halo)

typedef short short8 __attribute__((ext_vector_type(8)));
typedef float f32x4 __attribute__((ext_vector_type(4)));
typedef unsigned short u16x8 __attribute__((ext_vector_type(8)));

__device__ __forceinline__ unsigned short f2bf(float x) {
  union { float f; unsigned int u; } v; v.f = x;
  unsigned int r = v.u + 0x7FFF + ((v.u >> 16) & 1);   // RNE
  return (unsigned short)(r >> 16);
}
__device__ __forceinline__ float sigmoid_f(float x) {
  return 1.f / (1.f + __expf(-x));
}
__device__ __forceinline__ float tanh_f(float x) {
  float e = __expf(2.f * x);
  return 1.f - 2.f / (e + 1.f);
}

// ---- fused one-shot init, ALL REGIONS WRITE-DISJOINT (r18-verbatim, PASSED).
// Block ranges: [0,293) zero halo rings only, [293,1029) w0, [1029,2181) w1,
// [2181,2309) conv x(0) interior.
__global__ void init_all(const float* __restrict__ enc,
                         const float* __restrict__ W0, const float* __restrict__ W1,
                         unsigned short* __restrict__ h0a, unsigned short* __restrict__ h0b,
                         unsigned short* __restrict__ h1a, unsigned short* __restrict__ h1b,
                         unsigned short* __restrict__ xb0, unsigned short* __restrict__ xb1,
                         unsigned short* __restrict__ w0r, unsigned short* __restrict__ w1r)
{
  const int gb = blockIdx.x, tid = threadIdx.x;
  if (gb < 293) {
    int idx = gb * 256 + tid;
    u16x8 z = {};
    // x halo rings: 2 bufs x 8 b x 260 ring px x 2 chunks(16B) = 8320
    if (idx < 8320) {
      int bufi = idx / 4160, rem = idx - bufi * 4160;
      int b = rem / 520, r2 = rem - b * 520;
      int hp = r2 >> 1, c8 = r2 & 1;
      int y, x;
      if (hp < 66)       { y = 0;  x = hp; }
      else if (hp < 132) { y = 65; x = hp - 66; }
      else { int i2 = hp - 132; y = 1 + (i2 >> 1); x = (i2 & 1) * 65; }
      unsigned short* base = bufi ? xb1 : xb0;
      *(u16x8*)(base + ((size_t)((b * PH + y) * PH) + x) * 16 + c8 * 8) = z;
      return;
    }
    idx -= 8320;
    // h halo rings: 4 bufs x 8 b x 260 px x 8 chunks = 66560
    int bufi = idx / 16640;
    if (bufi >= 4) return;
    int rem = idx - bufi * 16640;
    int b = rem / 2080, r2 = rem - b * 2080;
    int hp = r2 >> 3, c8 = r2 & 7;
    int y, x;
    if (hp < 66)       { y = 0;  x = hp; }
    else if (hp < 132) { y = 65; x = hp - 66; }
    else { int i2 = hp - 132; y = 1 + (i2 >> 1); x = (i2 & 1) * 65; }
    unsigned short* base = (bufi == 0) ? h0a : (bufi == 1) ? h0b : (bufi == 2) ? h1a : h1b;
    *(u16x8*)(base + ((size_t)((b * PH + y) * PH) + x) * 64 + c8 * 8) = z;
  } else if (gb < 1029) {
    // W0 re-layout with x-tap pairing: 23 chunks.
    int o = (gb - 293) * 256 + tid;
    if (o >= 23 * 8192) return;
    int cc = o >> 13, t = o & 8191;
    int wn = t >> 11, t2 = t & 2047;
    int g = t2 >> 9, t3 = t2 & 511;
    int l = t3 >> 3, e = t3 & 7;
    int kg = l >> 4, r = l & 15;
    int k = kg * 8 + e;
    int col = g * 64 + wn * 16 + r;
    float v = 0.f;
    if (cc < 4) {
      int tap = 2 * cc + (k >> 4);
      v = W0[(size_t)(tap * 80 + (k & 15)) * 256 + col];
    } else if (cc == 4) {
      if (k < 16) v = W0[(size_t)(8 * 80 + k) * 256 + col];
    } else {
      int hcc = cc - 5, tap = hcc >> 1, cgi = hcc & 1;
      v = W0[(size_t)(tap * 80 + 16 + cgi * 32 + k) * 256 + col];
    }
    w0r[o] = f2bf(v);
  } else if (gb < 2181) {
    // W1 re-layout: 36 chunks [tap(9)][cgi(4)] of K=32.
    int o = (gb - 1029) * 256 + tid;
    if (o >= 36 * 8192) return;
    int cc = o >> 13, t = o & 8191;
    int wn = t >> 11, t2 = t & 2047;
    int g = t2 >> 9, t3 = t2 & 511;
    int l = t3 >> 3, e = t3 & 7;
    int kg = l >> 4, r = l & 15;
    int k = kg * 8 + e;
    int col = g * 64 + wn * 16 + r;
    int tap = cc >> 2, cgi = cc & 3;
    w1r[o] = f2bf(W1[(size_t)(tap * 128 + cgi * 32 + k) * 256 + col]);
  } else {
    // x(0) convert: enc fp32 -> padded bf16 [b][66][66][16] (interior only)
    int idx = (gb - 2181) * 256 + tid;                 // 32768
    int b = idx >> 12, pix = idx & 4095;
    int y = pix >> 6, x = pix & 63;
    const float* s = enc + ((size_t)(b * Tv + 0) * 4096 + pix) * 16;
    float4 f0 = *(const float4*)(s);
    float4 f1 = *(const float4*)(s + 4);
    float4 f2 = *(const float4*)(s + 8);
    float4 f3 = *(const float4*)(s + 12);
    u16x8 o0, o1;
    o0[0]=f2bf(f0.x); o0[1]=f2bf(f0.y); o0[2]=f2bf(f0.z); o0[3]=f2bf(f0.w);
    o0[4]=f2bf(f1.x); o0[5]=f2bf(f1.y); o0[6]=f2bf(f1.z); o0[7]=f2bf(f1.w);
    o1[0]=f2bf(f2.x); o1[1]=f2bf(f2.y); o1[2]=f2bf(f2.z); o1[3]=f2bf(f2.w);
    o1[4]=f2bf(f3.x); o1[5]=f2bf(f3.y); o1[6]=f2bf(f3.z); o1[7]=f2bf(f3.w);
    unsigned short* d = xb0 + ((size_t)((b * PH + y + 1) * PH) + (x + 1)) * 16;
    *(u16x8*)(d)     = o0;
    *(u16x8*)(d + 8) = o1;
  }
}

// ---- one cell on a 128-px (16x8) x 256-gate-col tile: 8 waves (2wm x 4wn).
// ASYMMETRIC LDS rings, 56KB total: A 3 bufs x 8KB (depth-2 in flight),
// W 2 bufs x 16KB (depth-1). 2 blocks x 56KB = 112KB << 160KB -> 2-block/CU
// co-residency. Per-phase VMEM bundle: [W(cc+1) x2, A(cc+2)] -> exact waits:
// steady vmcnt(1), last phase vmcnt(0). Buffer-reuse safety: W buf (cc+1)&1 /
// A buf (cc+2)%3 are last-read in phase cc-1; those ds_reads complete before
// each wave's MFMAs (data dep), which precede its barrier arrival; writes
// issue post-barrier. Raw s_barrier/chunk; setprio(1) around MFMA cluster.
// cell0 NC: 5 (T0) | 23; cell1 NC: 18 (T0) | 36.
template<int CELL, int NC>
__device__ __forceinline__ void cell_run(
    const char* __restrict__ A0, const char* __restrict__ A1,
    const char* __restrict__ Wr, const float* __restrict__ bias,
    float* __restrict__ cbuf, unsigned short* __restrict__ hout,
    float* __restrict__ h1fin, float* __restrict__ c1fin,
    char* lds, int b, int by, int bx, int tid)
{
  constexpr bool T0C = (CELL == 0) ? (NC == 5) : (NC == 18);
  const int l = tid & 63, w = tid >> 6;              // 8 waves
  const int wm = w >> 2, wn = w & 3;
  const int r = l & 15, kg = l >> 4;
  const int j = wn * 16 + r;

  char* ldsA = lds;                                  // 3 x 8KB
  char* ldsW = lds + 3 * 8192;                       // 2 x 16KB

  int pixs;                                          // wave stages A px-frag w
  {
    int ps = w * 16 + r;
    int ys = by * 16 + (ps >> 3), xs = bx * 8 + (ps & 7);
    pixs = (b * PH + ys) * PH + xs;                  // tap(0,0) in padded coords
  }
  const int zpix = b * PH * PH;                      // zeroed halo corner of batch b

  auto ISSUE_A = [&](int cc, int buf) {
    char* dst = ldsA + buf * 8192;
    if constexpr (CELL == 0) {
      if (cc < 5) {
        // paired-tap x chunk: kg<2 -> tap 2cc, kg>=2 -> tap 2cc+1 (cc==4: zeros)
        int tapA = 2 * cc;
        int kyA = tapA / 3, kxA = tapA - kyA * 3;
        unsigned offA = (unsigned)((pixs + kyA * PH + kxA) * 32 + kg * 16);
        unsigned offB;
        if (cc < 4) {
          int tapB = tapA + 1;
          int kyB = tapB / 3, kxB = tapB - kyB * 3;
          offB = (unsigned)((pixs + kyB * PH + kxB) * 32 + (kg - 2) * 16);
        } else {
          offB = (unsigned)(zpix * 32 + (kg - 2) * 16);
        }
        unsigned aoff = (kg < 2) ? offA : offB;
        __builtin_amdgcn_global_load_lds((const unsigned int*)(A0 + aoff),
                                         (unsigned int*)(dst + w * 1024), 16, 0, 0);
      } else {
        int hcc = cc - 5, tap = hcc >> 1, cgi = hcc & 1;
        int ky = tap / 3, kx = tap - ky * 3;
        unsigned aoff = (unsigned)((pixs + ky * PH + kx) * 128 + cgi * 64 + kg * 16);
        __builtin_amdgcn_global_load_lds((const unsigned int*)(A1 + aoff),
                                         (unsigned int*)(dst + w * 1024), 16, 0, 0);
      }
    } else {
      int tap, cgi;
      if (T0C) { tap = cc >> 1; cgi = cc & 1; }
      else     { tap = cc >> 2; cgi = cc & 3; }
      int ky = tap / 3, kx = tap - ky * 3;
      const char* srcb = (cgi < 2) ? A0 : A1;
      unsigned aoff = (unsigned)((pixs + ky * PH + kx) * 128 + (cgi & 1) * 64 + kg * 16);
      __builtin_amdgcn_global_load_lds((const unsigned int*)(srcb + aoff),
                                       (unsigned int*)(dst + w * 1024), 16, 0, 0);
    }
  };

  auto ISSUE_W = [&](int cc, int buf) {
    char* dst = ldsW + buf * 16384;
    int wcc;
    if constexpr (CELL == 0) wcc = cc;
    else                     wcc = T0C ? ((cc >> 1) * 4 + (cc & 1)) : cc;
    const char* wp = Wr + (size_t)wcc * 16384 + (unsigned)(w * 2048 + l * 16);
    __builtin_amdgcn_global_load_lds((const unsigned int*)(wp),
                                     (unsigned int*)(dst + w * 2048), 16, 0, 0);
    __builtin_amdgcn_global_load_lds((const unsigned int*)(wp + 1024),
                                     (unsigned int*)(dst + w * 2048 + 1024), 16, 0, 0);
  };

  f32x4 acc[4][4] = {};
  short8 af[4], bfv[4];

  // prologue, order pinned: W(0)x2, A(0), A(1)  -> top of phase 0: vmcnt(1)
  ISSUE_W(0, 0);
  __builtin_amdgcn_sched_barrier(0);
  ISSUE_A(0, 0);
  __builtin_amdgcn_sched_barrier(0);
  ISSUE_A(1, 1);
  __builtin_amdgcn_sched_barrier(0);

#pragma unroll
  for (int cc = 0; cc < NC; ++cc) {
    // W(cc) is the last-needed VMEM; exactly A(cc+1) (1 op) issued after it,
    // except at the final phase where nothing follows.
    if (cc == NC - 1) { asm volatile("s_waitcnt vmcnt(0)" ::: "memory"); }
    else              { asm volatile("s_waitcnt vmcnt(1)" ::: "memory"); }
    __builtin_amdgcn_sched_barrier(0);
    __builtin_amdgcn_s_barrier();                    // raw: no compiler vmcnt drain
    __builtin_amdgcn_sched_barrier(0);

    // bundle [W(cc+1) x2, A(cc+2)] — order pinned (vmcnt derivation).
    if (cc + 1 < NC) ISSUE_W(cc + 1, (cc + 1) & 1);
    __builtin_amdgcn_sched_barrier(0);
    if (cc + 2 < NC) ISSUE_A(cc + 2, (cc + 2) % 3);

    const char* bufA = ldsA + (cc % 3) * 8192;
    const char* bufW = ldsW + (cc & 1) * 16384;
#pragma unroll
    for (int mi = 0; mi < 4; ++mi)
      af[mi] = *(const short8*)(bufA + (wm * 4 + mi) * 1024 + l * 16);
#pragma unroll
    for (int g = 0; g < 4; ++g)
      bfv[g] = *(const short8*)(bufW + (wn * 4 + g) * 1024 + l * 16);

    __builtin_amdgcn_s_setprio(1);
#pragma unroll
    for (int mi = 0; mi < 4; ++mi)
#pragma unroll
      for (int g = 0; g < 4; ++g)
        acc[mi][g] = __builtin_amdgcn_mfma_f32_16x16x32_bf16(
            af[mi], bfv[g], acc[mi][g], 0, 0, 0);
    __builtin_amdgcn_s_setprio(0);
  }

  // ---- gates (c/bias loaded after the counted-vmcnt pipeline)
  float bi[4];
#pragma unroll
  for (int g = 0; g < 4; ++g) bi[g] = bias[g * 64 + j];
  float cpre[4][4];
#pragma unroll
  for (int mi = 0; mi < 4; ++mi) {
#pragma unroll
    for (int rg = 0; rg < 4; ++rg) {
      if constexpr (T0C) { cpre[mi][rg] = 0.f; }
      else {
        int p = wm * 64 + mi * 16 + kg * 4 + rg;
        int y = by * 16 + (p >> 3), x = bx * 8 + (p & 7);
        cpre[mi][rg] = cbuf[((size_t)((b * Hv + y) * Wv) + x) * HID + j];
      }
    }
  }
#pragma unroll
  for (int mi = 0; mi < 4; ++mi) {
#pragma unroll
    for (int rg = 0; rg < 4; ++rg) {
      int p = wm * 64 + mi * 16 + kg * 4 + rg;       // C/D row = (lane>>4)*4 + reg
      int y = by * 16 + (p >> 3), x = bx * 8 + (p & 7);
      float zi = acc[mi][0][rg] + bi[0];
      float zf = acc[mi][1][rg] + bi[1];
      float zo = acc[mi][2][rg] + bi[2];
      float zg = acc[mi][3][rg] + bi[3];
      float cn = sigmoid_f(zf) * cpre[mi][rg] + sigmoid_f(zi) * tanh_f(zg);
      float hn = sigmoid_f(zo) * tanh_f(cn);
      size_t ci = ((size_t)((b * Hv + y) * Wv) + x) * HID + j;
      cbuf[ci] = cn;
      hout[((size_t)((b * PH + y + 1) * PH) + (x + 1)) * HID + j] = f2bf(hn);
      if (CELL == 1 && h1fin != nullptr) {
        h1fin[ci] = hn;
        c1fin[ci] = cn;
      }
    }
  }
}

// ---- fused dispatch D(t): cell1(t-1) || cell0(t) as block roles (independent).
// 512-thr blocks, 56KB LDS -> 2 blocks/CU co-resident. Role split by gid<256:
// HW assigns gid g and g+256 to the same CU -> each CU hosts one cell1 (36
// chunks) + one cell0 (23 chunks) block.
template<int NC1, int NC0, bool LAST>
__global__ __launch_bounds__(512, 4)
void step_fused(const unsigned short* __restrict__ xbr, unsigned short* __restrict__ xbw,
                const unsigned short* __restrict__ h0r, unsigned short* __restrict__ h0w,
                const unsigned short* __restrict__ h1r, unsigned short* __restrict__ h1w,
                const unsigned short* __restrict__ w0r, const unsigned short* __restrict__ w1r,
                const float* __restrict__ b0, const float* __restrict__ b1,
                float* __restrict__ c0, float* __restrict__ c1,
                float* __restrict__ h1f, float* __restrict__ c1f,
                const float* __restrict__ enc, int tnext)
{
  extern __shared__ char lds[];
  const int tid = threadIdx.x;
  const int gid = blockIdx.x;
  int isC1, k;
  if constexpr (NC1 > 0 && NC0 > 0) { isC1 = (gid < 256) ? 1 : 0; k = gid & 255; }
  else if constexpr (NC1 > 0)       { isC1 = 1; k = gid; }
  else                              { isC1 = 0; k = gid; }
  const int b = k >> 5, rem = k & 31;
  const int by = rem >> 3, bx = rem & 7;             // 16x8 px tile

  if constexpr (NC1 > 0) {
    if (isC1) {
      cell_run<1, NC1>((const char*)h0r, (const char*)h1r, (const char*)w1r, b1,
                       c1, h1w, LAST ? h1f : nullptr, LAST ? c1f : nullptr,
                       lds, b, by, bx, tid);
      return;
    }
  }
  if constexpr (NC0 > 0) {
    cell_run<0, NC0>((const char*)xbr, (const char*)h0r, (const char*)w0r, b0,
                     c0, h0w, nullptr, nullptr, lds, b, by, bx, tid);
    if (tnext >= 0) {                                // convert own 128-px tile of x(tnext)
      int pp = tid >> 2, q4 = tid & 3;
      int y = by * 16 + (pp >> 3), x = bx * 8 + (pp & 7);
      const float* s = enc + ((size_t)(b * Tv + tnext) * 4096 + (y * 64 + x)) * 16 + q4 * 4;
      float4 f = *(const float4*)s;
      unsigned short* d = xbw + ((size_t)((b * PH + y + 1) * PH) + (x + 1)) * 16 + q4 * 4;
      d[0] = f2bf(f.x); d[1] = f2bf(f.y); d[2] = f2bf(f.z); d[3] = f2bf(f.w);
    }
  }
}

extern "C" void kernel_launch(void* const* d_in, const int* in_sizes, int n_in,
                              void* d_out, int out_size, void* d_ws, size_t ws_size,
                              hipStream_t stream) {
  const float* enc = (const float*)d_in[0];
  const float* W0  = (const float*)d_in[1];
  const float* b0  = (const float*)d_in[2];
  const float* W1  = (const float*)d_in[3];
  const float* b1  = (const float*)d_in[4];

  float* out = (float*)d_out;
  const size_t NST = (size_t)Bv * Hv * Wv * HID;     // 2,097,152
  float* h1f = out;                                   // final h1 (fp32)
  float* c1  = out + NST;                             // c1 running state (fp32, in-place)

  char* ws = (char*)d_ws;
  const size_t SZ_C = NST * 4;                        // 8,388,608
  const size_t SZ_H = (size_t)Bv * PH * PH * HID * 2; // 4,460,544
  const size_t SZ_X = (size_t)Bv * PH * PH * 16 * 2;  // 1,115,136 (16ch rows)
  float*          c0  = (float*)ws;
  unsigned short* h0a = (unsigned short*)(ws + SZ_C);
  unsigned short* h0b = (unsigned short*)(ws + SZ_C + SZ_H);
  unsigned short* h1a = (unsigned short*)(ws + SZ_C + 2 * SZ_H);
  unsigned short* h1b = (unsigned short*)(ws + SZ_C + 3 * SZ_H);
  unsigned short* xb0 = (unsigned short*)(ws + SZ_C + 4 * SZ_H);
  unsigned short* xb1 = (unsigned short*)(ws + SZ_C + 4 * SZ_H + SZ_X);
  unsigned short* w0r = (unsigned short*)(ws + SZ_C + 4 * SZ_H + 2 * SZ_X);
  unsigned short* w1r = (unsigned short*)(ws + SZ_C + 4 * SZ_H + 2 * SZ_X + (size_t)23 * 16384);

  hipFuncSetAttribute((const void*)step_fused<0,5,false>,   hipFuncAttributeMaxDynamicSharedMemorySize, 65536);
  hipFuncSetAttribute((const void*)step_fused<18,23,false>, hipFuncAttributeMaxDynamicSharedMemorySize, 65536);
  hipFuncSetAttribute((const void*)step_fused<36,23,false>, hipFuncAttributeMaxDynamicSharedMemorySize, 65536);
  hipFuncSetAttribute((const void*)step_fused<36,0,true>,   hipFuncAttributeMaxDynamicSharedMemorySize, 65536);

  // single fused init (write-disjoint regions): x/h halo zeroing + W
  // re-layouts + x(0) interior convert
  init_all<<<2309, 256, 0, stream>>>(enc, W0, W1, h0a, h0b, h1a, h1b,
                                     xb0, xb1, w0r, w1r);

  const int LDSB = 57344;                            // A 3x8KB + W 2x16KB
  // D(0): cell0(0) T0 (x chunks only); converts x(1) -> xb1
  step_fused<0,5,false><<<256, 512, LDSB, stream>>>(
      xb0, xb1, h0b, h0a, h1a, h1b, w0r, w1r, b0, b1, c0, c1,
      nullptr, nullptr, enc, 1);
  // D(t), t=1..15: cell1(t-1) || cell0(t) (+ convert x(t+1))
  for (int t = 1; t <= 15; ++t) {
    unsigned short* h0r = (t & 1) ? h0a : h0b;       // h0buf[(t-1)&1]
    unsigned short* h0w = (t & 1) ? h0b : h0a;       // h0buf[t&1]
    unsigned short* h1r = (t & 1) ? h1b : h1a;       // h1buf[t&1] (= h1(t-2))
    unsigned short* h1w = (t & 1) ? h1a : h1b;       // h1buf[(t-1)&1]
    unsigned short* xr  = (t & 1) ? xb1 : xb0;
    unsigned short* xw  = (t & 1) ? xb0 : xb1;
    int tn = (t + 1 <= 15) ? (t + 1) : -1;
    if (t == 1)
      step_fused<18,23,false><<<512, 512, LDSB, stream>>>(
          xr, xw, h0r, h0w, h1r, h1w, w0r, w1r, b0, b1, c0, c1,
          nullptr, nullptr, enc, tn);
    else
      step_fused<36,23,false><<<512, 512, LDSB, stream>>>(
          xr, xw, h0r, h0w, h1r, h1w, w0r, w1r, b0, b1, c0, c1,
          nullptr, nullptr, enc, tn);
  }
  // D(16): cell1(15) alone -> writes h1f/c1f
  step_fused<36,0,true><<<256, 512, LDSB, stream>>>(
      xb0, xb1, h0b, h0a, h1a, h1b, w0r, w1r, b0, b1, c0, c1,
      h1f, c1, enc, -1);
}